// Round 12
// baseline (185.303 us; speedup 1.0000x reference)
//
#include <hip/hip_runtime.h>
#include <math.h>

// Problem constants (fixed by setup_inputs)
#define W_ 192
#define H_ 192
#define D_ 160
#define B_ 2
#define HW_ (H_ * W_)

// Single-wave block: 64 threads, TX=16 x TY=8 tile.
// __syncthreads() on a 64-thread block = in-wave fence (no s_barrier).
#define TX 16
#define TY 8
#define HY 12             // halo rows (TY + 4)
#define SCOLS 24          // staged cols (aligned float4 span covering 20-col halo)
#define RAWP 25           // raw row stride (odd)
#define RSP  24           // rs row stride: 2*RSP%32==16 -> phase2 reads 2-way max
#define CHUNK 20          // z-planes of output per block
#define PLANES (CHUNK + 4)
#define GX 12             // 192/16
#define GY 24             // 192/8
#define GZ 16             // 8 z-chunks * 2 batches
#define NBLK (GX * GY * GZ)   // 4608
#define NTOT 11796480.0f      // 2*1*160*192*192

__global__ __launch_bounds__(64) void lncc_main(const float* __restrict__ src,
                                                const float* __restrict__ tgt,
                                                float* __restrict__ partial) {
    // raw: double-buffered; rs: single-buffered (fences are in-wave, ~free).
    // LDS = (2*12*25*2 + 5*12*24) * 4 = 10560 B -> ~15 blocks/CU resident.
    __shared__ float rawS[2][HY][RAWP];
    __shared__ float rawT[2][HY][RAWP];
    __shared__ float rsS [HY][RSP];
    __shared__ float rsT [HY][RSP];
    __shared__ float rsS2[HY][RSP];
    __shared__ float rsT2[HY][RSP];
    __shared__ float rsST[HY][RSP];

    const int tid = threadIdx.x;
    const int bz  = blockIdx.z;
    const int b   = bz >> 3;                 // 8 chunks per batch
    const int z0  = (bz & 7) * CHUNK;
    const int bx0 = blockIdx.x * TX - 4;     // staged col 0 <-> gx = bx0 (x4 aligned)
    const int by0 = blockIdx.y * TY - 2;

    // ---- staging decode: 12 rows x 6 float4 = 72 slots, two reps ----
    // rep0: slot = tid (0..63); rep1: slot = 64+tid (tid<8).
    const int  s0row = tid / 6,        s0c = (tid - s0row * 6) * 4;
    const int  s1slt = 64 + tid;
    const int  s1row = s1slt / 6,      s1c = (s1slt - s1row * 6) * 4;
    const bool s1W   = (tid < 8);
    const int  s0gx = bx0 + s0c,  s0gy = by0 + s0row;
    const int  s1gx = bx0 + s1c,  s1gy = by0 + s1row;
    const bool s0Ok = ((unsigned)s0gx < (unsigned)W_) && ((unsigned)s0gy < (unsigned)H_);
    const bool s1Ok = s1W && ((unsigned)s1gx < (unsigned)W_) && ((unsigned)s1gy < (unsigned)H_);
    const size_t s0Off = (size_t)s0gy * W_ + (size_t)s0gx;
    const size_t s1Off = (size_t)s1gy * W_ + (size_t)s1gx;

    // ---- phase1 decode: 12 rows x 8 x-pairs = 96 slots, two reps ----
    const int  xp   = tid & 7;
    const int  p0y  = tid >> 3;              // rows 0..7 (all threads)
    const int  p1y  = 8 + (tid >> 3);        // rows 8..11 (tid<32)
    const bool p1   = (tid < 32);
    const int  rc   = 2 * xp + 2;            // raw read col base (reads rc..rc+5)
    const int  wc   = 2 * xp;                // rs write col base

    // ---- phase2 decode: thread owns output rows (y0, y0+1) at column tx ----
    const int tx = tid & 15;                 // 0..15
    const int y0 = (tid >> 4) * 2;           // 0,2,4,6

    // z-ring as float2 (x = row y0, y = row y0+1). NAMED scalars only (rule #20).
    float2 q0s=make_float2(0,0),q0t=make_float2(0,0),q0a=make_float2(0,0),q0b=make_float2(0,0),q0c=make_float2(0,0);
    float2 q1s=make_float2(0,0),q1t=make_float2(0,0),q1a=make_float2(0,0),q1b=make_float2(0,0),q1c=make_float2(0,0);
    float2 q2s=make_float2(0,0),q2t=make_float2(0,0),q2a=make_float2(0,0),q2b=make_float2(0,0),q2c=make_float2(0,0);
    float2 q3s=make_float2(0,0),q3t=make_float2(0,0),q3a=make_float2(0,0),q3b=make_float2(0,0),q3c=make_float2(0,0);
    float2 q4s=make_float2(0,0),q4t=make_float2(0,0),q4a=make_float2(0,0),q4b=make_float2(0,0),q4c=make_float2(0,0);
    float2 zS=make_float2(0,0),zT=make_float2(0,0),zA=make_float2(0,0),zB=make_float2(0,0),zC=make_float2(0,0);
    float lsum = 0.0f;

    // phase2: 6-row y-sums (pair shares middle 4) + z-window + LNCC, lag-0.
    auto phase2 = [&](int j) {
        float2 yS, yT, yA, yB, yC;
        {
            const float* p = &rsS[y0][tx];
            float l0=p[0], l1=p[RSP], l2=p[2*RSP], l3=p[3*RSP], l4=p[4*RSP], l5=p[5*RSP];
            float m = l1 + l2 + l3 + l4;
            yS.x = l0 + m;  yS.y = m + l5;
        }
        {
            const float* p = &rsT[y0][tx];
            float l0=p[0], l1=p[RSP], l2=p[2*RSP], l3=p[3*RSP], l4=p[4*RSP], l5=p[5*RSP];
            float m = l1 + l2 + l3 + l4;
            yT.x = l0 + m;  yT.y = m + l5;
        }
        {
            const float* p = &rsS2[y0][tx];
            float l0=p[0], l1=p[RSP], l2=p[2*RSP], l3=p[3*RSP], l4=p[4*RSP], l5=p[5*RSP];
            float m = l1 + l2 + l3 + l4;
            yA.x = l0 + m;  yA.y = m + l5;
        }
        {
            const float* p = &rsT2[y0][tx];
            float l0=p[0], l1=p[RSP], l2=p[2*RSP], l3=p[3*RSP], l4=p[4*RSP], l5=p[5*RSP];
            float m = l1 + l2 + l3 + l4;
            yB.x = l0 + m;  yB.y = m + l5;
        }
        {
            const float* p = &rsST[y0][tx];
            float l0=p[0], l1=p[RSP], l2=p[2*RSP], l3=p[3*RSP], l4=p[4*RSP], l5=p[5*RSP];
            float m = l1 + l2 + l3 + l4;
            yC.x = l0 + m;  yC.y = m + l5;
        }
        zS.x += yS.x - q0s.x;  zS.y += yS.y - q0s.y;
        zT.x += yT.x - q0t.x;  zT.y += yT.y - q0t.y;
        zA.x += yA.x - q0a.x;  zA.y += yA.y - q0a.y;
        zB.x += yB.x - q0b.x;  zB.y += yB.y - q0b.y;
        zC.x += yC.x - q0c.x;  zC.y += yC.y - q0c.y;
        q0s=q1s; q0t=q1t; q0a=q1a; q0b=q1b; q0c=q1c;
        q1s=q2s; q1t=q2t; q1a=q2a; q1b=q2b; q1c=q2c;
        q2s=q3s; q2t=q3t; q2a=q3a; q2b=q3b; q2c=q3c;
        q3s=q4s; q3t=q4t; q3a=q4a; q3b=q4b; q3c=q4c;
        q4s=yS;  q4t=yT;  q4a=yA;  q4b=yB;  q4c=yC;
        if (j >= 4) {
            const float inv = 1.0f / 125.0f;
            {
                float ms = zS.x * inv, mt = zT.x * inv;
                float vs = fmaf(-ms, ms, zA.x * inv);
                float vt = fmaf(-mt, mt, zB.x * inv);
                float cr = fmaf(-ms, mt, zC.x * inv);
                float den = fmaf(vs, vt, 1e-5f);
                lsum = fmaf(cr * cr, __builtin_amdgcn_rcpf(den), lsum);
            }
            {
                float ms = zS.y * inv, mt = zT.y * inv;
                float vs = fmaf(-ms, ms, zA.y * inv);
                float vt = fmaf(-mt, mt, zB.y * inv);
                float cr = fmaf(-ms, mt, zC.y * inv);
                float den = fmaf(vs, vt, 1e-5f);
                lsum = fmaf(cr * cr, __builtin_amdgcn_rcpf(den), lsum);
            }
        }
    };

    // phase1: sliding x-window, 6 raw words -> 2 rowsums per array
    auto rowsum = [&](int buf, int row) {
        const float* pS = &rawS[buf][row][rc];
        const float* pT = &rawT[buf][row][rc];
        float v0=pS[0],v1=pS[1],v2=pS[2],v3=pS[3],v4=pS[4],v5=pS[5];
        float u0=pT[0],u1=pT[1],u2=pT[2],u3=pT[3],u4=pT[4],u5=pT[5];
        float m  = v1 + v2 + v3 + v4;
        float n  = u1 + u2 + u3 + u4;
        float qS = fmaf(v1,v1, fmaf(v2,v2, fmaf(v3,v3, v4*v4)));
        float qT = fmaf(u1,u1, fmaf(u2,u2, fmaf(u3,u3, u4*u4)));
        float qX = fmaf(v1,u1, fmaf(v2,u2, fmaf(v3,u3, v4*u4)));
        rsS [row][wc]   = v0 + m;
        rsS [row][wc+1] = m + v5;
        rsT [row][wc]   = u0 + n;
        rsT [row][wc+1] = n + u5;
        rsS2[row][wc]   = fmaf(v0,v0,qS);
        rsS2[row][wc+1] = fmaf(v5,v5,qS);
        rsT2[row][wc]   = fmaf(u0,u0,qT);
        rsT2[row][wc+1] = fmaf(u5,u5,qT);
        rsST[row][wc]   = fmaf(v0,u0,qX);
        rsST[row][wc+1] = fmaf(v5,u5,qX);
    };

    auto stageWrite = [&](int buf, const float4& v0S, const float4& v0T,
                          const float4& v1S, const float4& v1T) {
        rawS[buf][s0row][s0c]=v0S.x; rawS[buf][s0row][s0c+1]=v0S.y;
        rawS[buf][s0row][s0c+2]=v0S.z; rawS[buf][s0row][s0c+3]=v0S.w;
        rawT[buf][s0row][s0c]=v0T.x; rawT[buf][s0row][s0c+1]=v0T.y;
        rawT[buf][s0row][s0c+2]=v0T.z; rawT[buf][s0row][s0c+3]=v0T.w;
        if (s1W) {
            rawS[buf][s1row][s1c]=v1S.x; rawS[buf][s1row][s1c+1]=v1S.y;
            rawS[buf][s1row][s1c+2]=v1S.z; rawS[buf][s1row][s1c+3]=v1S.w;
            rawT[buf][s1row][s1c]=v1T.x; rawT[buf][s1row][s1c+1]=v1T.y;
            rawT[buf][s1row][s1c+2]=v1T.z; rawT[buf][s1row][s1c+3]=v1T.w;
        }
    };

    // ---- prologue: stage plane z0-2 into raw[0] ----
    {
        float4 a0S=make_float4(0,0,0,0), a0T=make_float4(0,0,0,0);
        float4 a1S=make_float4(0,0,0,0), a1T=make_float4(0,0,0,0);
        const int zp = z0 - 2;
        if (zp >= 0) {
            const size_t base = (size_t)(b * D_ + zp) * (size_t)HW_;
            if (s0Ok) { a0S = *(const float4*)(src + base + s0Off);
                        a0T = *(const float4*)(tgt + base + s0Off); }
            if (s1Ok) { a1S = *(const float4*)(src + base + s1Off);
                        a1T = *(const float4*)(tgt + base + s1Off); }
        }
        stageWrite(0, a0S, a0T, a1S, a1T);
    }

    for (int i = 0; i < PLANES; ++i) {
        const int buf = i & 1;
        __syncthreads();   // in-wave fence: raw[buf] staged & visible; rs free
        // -- issue global loads for plane i+1 --
        float4 a0S=make_float4(0,0,0,0), a0T=make_float4(0,0,0,0);
        float4 a1S=make_float4(0,0,0,0), a1T=make_float4(0,0,0,0);
        const bool haveNext = (i + 1 < PLANES);
        const int  zpn = z0 - 1 + i;
        if (haveNext && zpn >= 0 && zpn < D_) {
            const size_t base = (size_t)(b * D_ + zpn) * (size_t)HW_;
            if (s0Ok) { a0S = *(const float4*)(src + base + s0Off);
                        a0T = *(const float4*)(tgt + base + s0Off); }
            if (s1Ok) { a1S = *(const float4*)(src + base + s1Off);
                        a1T = *(const float4*)(tgt + base + s1Off); }
        }
        // -- phase1: raw[buf] -> rs (single buffer) --
        rowsum(buf, p0y);
        if (p1) rowsum(buf, p1y);
        __syncthreads();   // in-wave fence: rs ready
        // -- phase2 (lag-0) --
        phase2(i);
        // -- write staged plane i+1 into raw[buf^1] (vmcnt lands here) --
        if (haveNext) stageWrite(buf ^ 1, a0S, a0T, a1S, a1T);
    }

    // single-wave reduction -> per-block partial
    #pragma unroll
    for (int off = 32; off > 0; off >>= 1)
        lsum += __shfl_down(lsum, off, 64);
    if (tid == 0) {
        const int bid = (blockIdx.z * GY + blockIdx.y) * GX + blockIdx.x;
        partial[bid] = lsum;
    }
}

__global__ __launch_bounds__(256) void lncc_finalize(const float* __restrict__ partial,
                                                     float* __restrict__ out) {
    __shared__ float ws[4];
    const int t = threadIdx.x;
    float s = 0.0f;
    for (int i = t; i < NBLK; i += 256) s += partial[i];
    #pragma unroll
    for (int off = 32; off > 0; off >>= 1) s += __shfl_down(s, off, 64);
    if ((t & 63) == 0) ws[t >> 6] = s;
    __syncthreads();
    if (t == 0) {
        float tot = ws[0] + ws[1] + ws[2] + ws[3];
        float loss = 1.0f - tot * (1.0f / NTOT);
        if (isnan(loss) || isinf(loss)) loss = 1.0f;
        *out = loss;
    }
}

extern "C" void kernel_launch(void* const* d_in, const int* in_sizes, int n_in,
                              void* d_out, int out_size, void* d_ws, size_t ws_size,
                              hipStream_t stream) {
    const float* src = (const float*)d_in[0];
    const float* tgt = (const float*)d_in[1];
    float* out = (float*)d_out;
    float* partial = (float*)d_ws;   // NBLK floats of scratch

    dim3 grid(GX, GY, GZ);           // 12 x 24 x 16 = 4608 single-wave blocks
    dim3 block(64, 1, 1);
    lncc_main<<<grid, block, 0, stream>>>(src, tgt, partial);
    lncc_finalize<<<dim3(1), dim3(256), 0, stream>>>(partial, out);
}

// Round 14
// 160.785 us; speedup vs baseline: 1.1525x; 1.1525x over previous
//
#include <hip/hip_runtime.h>
#include <math.h>

// Problem constants (fixed by setup_inputs)
#define W_ 192
#define H_ 192
#define D_ 160
#define B_ 2
#define HW_ (H_ * W_)

#define TX 32             // output tile x
#define TY 6              // output tile y (8->6: LDS under 20KB -> 8 blocks/CU)
#define HY 10             // halo rows (TY + 4)
#define RAWP 41           // raw row stride, 40 data cols + odd stride (<=2-way banks)
#define RSP  33           // rowsum row stride, 32 data cols + odd stride (<=2-way banks)
#define CHUNK 20          // z-planes of output per block
#define PLANES (CHUNK + 4)
#define GX 6              // 192/32
#define GY 32             // 192/6
#define GZ 16             // 8 z-chunks * 2 batches
#define NBLK (GX * GY * GZ)   // 3072 (12/CU queued, 8 resident)
#define NTOT 11796480.0f      // 2*1*160*192*192

__global__ __launch_bounds__(256) void lncc_main(const float* __restrict__ src,
                                                 const float* __restrict__ tgt,
                                                 float* __restrict__ partial) {
    // SoA float LDS, double-buffered, 1 barrier/plane (champion structure).
    // Total 19776 B -> 8 blocks/CU resident = 32 waves/CU (hardware cap).
    __shared__ float rawS[2][HY][RAWP];
    __shared__ float rawT[2][HY][RAWP];
    __shared__ float rsS [2][HY][RSP];
    __shared__ float rsT [2][HY][RSP];
    __shared__ float rsS2[2][HY][RSP];
    __shared__ float rsT2[2][HY][RSP];
    __shared__ float rsST[2][HY][RSP];
    __shared__ float wsum[4];

    const int tid = threadIdx.x;
    const int bz  = blockIdx.z;
    const int b   = bz >> 3;                 // 8 chunks per batch
    const int z0  = (bz & 7) * CHUNK;
    const int bx0 = blockIdx.x * TX - 4;     // raw col 0 <-> gx = bx0 (16B-aligned)
    const int by0 = blockIdx.y * TY - 2;

    // ---- staging decode: tid<100 loads one aligned float4 per array ----
    const int  sr  = tid / 10;               // row 0..9
    const int  sc4 = tid - sr * 10;          // float4 col 0..9
    const int  sc  = sc4 * 4;                // word col 0,4,..,36
    const int  sgx = bx0 + sc;               // multiple of 4 -> float4 aligned
    const int  sgy = by0 + sr;
    const bool sW  = (tid < 100);
    const bool sOk = sW && ((unsigned)sgx < (unsigned)W_) && ((unsigned)sgy < (unsigned)H_);
    const size_t sOff = (size_t)sgy * W_ + (size_t)sgx;   // valid only when sOk

    // ---- phase1 decode: 16 x-pairs x 10 rows = 160 threads, one rep ----
    const int  p0y = tid >> 4;               // row (only tid<160 active)
    const int  xp  = tid & 15;
    const bool pAct = (tid < 160);
    const int  rc  = 2 * xp + 2;             // raw read col base (window of out 2*xp)
    const int  wc  = 2 * xp;                 // rs write col base

    // ---- phase2 decode: thread owns output row y0, column tx (tid<192) ----
    const int tx = tid & 31;                 // 0..31
    const int y0 = tid >> 5;                 // 0..7 (only 0..5 active)
    const bool qAct = (tid < 192);           // guard: y0 <= 5 keeps reads in HY

    // z-ring: NAMED scalars only (arrays -> scratch: round-4 disaster, rule #20).
    float q0s=0,q0t=0,q0a=0,q0b=0,q0c=0;
    float q1s=0,q1t=0,q1a=0,q1b=0,q1c=0;
    float q2s=0,q2t=0,q2a=0,q2b=0,q2c=0;
    float q3s=0,q3t=0,q3a=0,q3b=0,q3c=0;
    float q4s=0,q4t=0,q4a=0,q4b=0,q4c=0;
    float zS=0,zT=0,zA=0,zB=0,zC=0;
    float lsum = 0.0f;

    // phase2: y-sum of rowsums for plane j (buffer rbuf) + z-window + LNCC
    auto phase2 = [&](int rbuf, int j) {
        if (!qAct) return;
        float yS,yT,yA,yB,yC;
        {
            const float* p = &rsS[rbuf][y0][tx];
            yS = p[0] + p[RSP] + p[2*RSP] + p[3*RSP] + p[4*RSP];
        }
        {
            const float* p = &rsT[rbuf][y0][tx];
            yT = p[0] + p[RSP] + p[2*RSP] + p[3*RSP] + p[4*RSP];
        }
        {
            const float* p = &rsS2[rbuf][y0][tx];
            yA = p[0] + p[RSP] + p[2*RSP] + p[3*RSP] + p[4*RSP];
        }
        {
            const float* p = &rsT2[rbuf][y0][tx];
            yB = p[0] + p[RSP] + p[2*RSP] + p[3*RSP] + p[4*RSP];
        }
        {
            const float* p = &rsST[rbuf][y0][tx];
            yC = p[0] + p[RSP] + p[2*RSP] + p[3*RSP] + p[4*RSP];
        }
        zS += yS - q0s;  zT += yT - q0t;  zA += yA - q0a;
        zB += yB - q0b;  zC += yC - q0c;
        q0s=q1s; q0t=q1t; q0a=q1a; q0b=q1b; q0c=q1c;
        q1s=q2s; q1t=q2t; q1a=q2a; q1b=q2b; q1c=q2c;
        q2s=q3s; q2t=q3t; q2a=q3a; q2b=q3b; q2c=q3c;
        q3s=q4s; q3t=q4t; q3a=q4a; q3b=q4b; q3c=q4c;
        q4s=yS;  q4t=yT;  q4a=yA;  q4b=yB;  q4c=yC;
        if (j >= 4) {
            const float inv = 1.0f / 125.0f;
            float ms = zS * inv, mt = zT * inv;
            float vs = fmaf(-ms, ms, zA * inv);
            float vt = fmaf(-mt, mt, zB * inv);
            float cr = fmaf(-ms, mt, zC * inv);
            float den = fmaf(vs, vt, 1e-5f);
            lsum = fmaf(cr * cr, __builtin_amdgcn_rcpf(den), lsum);
        }
    };

    // phase1: sliding x-window, 6 raw words -> 2 rowsums per array
    auto rowsum = [&](int buf, int row) {
        const float* pS = &rawS[buf][row][rc];
        const float* pT = &rawT[buf][row][rc];
        float v0=pS[0],v1=pS[1],v2=pS[2],v3=pS[3],v4=pS[4],v5=pS[5];
        float u0=pT[0],u1=pT[1],u2=pT[2],u3=pT[3],u4=pT[4],u5=pT[5];
        float m  = v1 + v2 + v3 + v4;
        float n  = u1 + u2 + u3 + u4;
        float qS = fmaf(v1,v1, fmaf(v2,v2, fmaf(v3,v3, v4*v4)));
        float qT = fmaf(u1,u1, fmaf(u2,u2, fmaf(u3,u3, u4*u4)));
        float qX = fmaf(v1,u1, fmaf(v2,u2, fmaf(v3,u3, v4*u4)));
        rsS [buf][row][wc]   = v0 + m;
        rsS [buf][row][wc+1] = m + v5;
        rsT [buf][row][wc]   = u0 + n;
        rsT [buf][row][wc+1] = n + u5;
        rsS2[buf][row][wc]   = fmaf(v0,v0,qS);
        rsS2[buf][row][wc+1] = fmaf(v5,v5,qS);
        rsT2[buf][row][wc]   = fmaf(u0,u0,qT);
        rsT2[buf][row][wc+1] = fmaf(u5,u5,qT);
        rsST[buf][row][wc]   = fmaf(v0,u0,qX);
        rsST[buf][row][wc+1] = fmaf(v5,u5,qX);
    };

    // ---- prologue: stage plane zp = z0-2 into raw[0] ----
    {
        float4 vS = make_float4(0,0,0,0), vT = make_float4(0,0,0,0);
        const int zp = z0 - 2;
        if (zp >= 0 && sOk) {
            const size_t base = (size_t)(b * D_ + zp) * (size_t)HW_;
            vS = *(const float4*)(src + base + sOff);
            vT = *(const float4*)(tgt + base + sOff);
        }
        if (sW) {
            rawS[0][sr][sc]=vS.x; rawS[0][sr][sc+1]=vS.y; rawS[0][sr][sc+2]=vS.z; rawS[0][sr][sc+3]=vS.w;
            rawT[0][sr][sc]=vT.x; rawT[0][sr][sc+1]=vT.y; rawT[0][sr][sc+2]=vT.z; rawT[0][sr][sc+3]=vT.w;
        }
    }

    for (int i = 0; i < PLANES; ++i) {
        const int buf = i & 1;
        __syncthreads();   // the ONLY barrier per plane
        // -- issue global loads for plane i+1 (consumed at loop end) --
        float4 vS = make_float4(0,0,0,0), vT = make_float4(0,0,0,0);
        const bool haveNext = (i + 1 < PLANES);
        const int  zpn = z0 - 1 + i;
        if (haveNext && zpn >= 0 && zpn < D_ && sOk) {
            const size_t base = (size_t)(b * D_ + zpn) * (size_t)HW_;
            vS = *(const float4*)(src + base + sOff);
            vT = *(const float4*)(tgt + base + sOff);
        }
        // -- phase2 for plane i-1 (rowsums written last iteration) --
        if (i >= 1) phase2(buf ^ 1, i - 1);
        // -- phase1 for plane i: x-rowsums raw[buf] -> rs[buf] --
        if (pAct) rowsum(buf, p0y);
        // -- write staged plane i+1 into raw[buf^1] (vmcnt wait lands here) --
        if (haveNext && sW) {
            rawS[buf^1][sr][sc]=vS.x; rawS[buf^1][sr][sc+1]=vS.y; rawS[buf^1][sr][sc+2]=vS.z; rawS[buf^1][sr][sc+3]=vS.w;
            rawT[buf^1][sr][sc]=vT.x; rawT[buf^1][sr][sc+1]=vT.y; rawT[buf^1][sr][sc+2]=vT.z; rawT[buf^1][sr][sc+3]=vT.w;
        }
    }
    __syncthreads();
    phase2((PLANES - 1) & 1, PLANES - 1);   // drain the pipeline

    // block reduction -> per-block partial (no atomics, no zero-kernel)
    #pragma unroll
    for (int off = 32; off > 0; off >>= 1)
        lsum += __shfl_down(lsum, off, 64);
    if ((tid & 63) == 0) wsum[tid >> 6] = lsum;
    __syncthreads();
    if (tid == 0) {
        const int bid = (blockIdx.z * GY + blockIdx.y) * GX + blockIdx.x;
        partial[bid] = wsum[0] + wsum[1] + wsum[2] + wsum[3];
    }
}

__global__ __launch_bounds__(256) void lncc_finalize(const float* __restrict__ partial,
                                                     float* __restrict__ out) {
    __shared__ float ws[4];
    const int t = threadIdx.x;
    float s = 0.0f;
    for (int i = t; i < NBLK; i += 256) s += partial[i];
    #pragma unroll
    for (int off = 32; off > 0; off >>= 1) s += __shfl_down(s, off, 64);
    if ((t & 63) == 0) ws[t >> 6] = s;
    __syncthreads();
    if (t == 0) {
        float tot = ws[0] + ws[1] + ws[2] + ws[3];
        float loss = 1.0f - tot * (1.0f / NTOT);
        if (isnan(loss) || isinf(loss)) loss = 1.0f;
        *out = loss;
    }
}

extern "C" void kernel_launch(void* const* d_in, const int* in_sizes, int n_in,
                              void* d_out, int out_size, void* d_ws, size_t ws_size,
                              hipStream_t stream) {
    const float* src = (const float*)d_in[0];
    const float* tgt = (const float*)d_in[1];
    float* out = (float*)d_out;
    float* partial = (float*)d_ws;   // NBLK floats of scratch

    dim3 grid(GX, GY, GZ);           // 6 x 32 x 16 = 3072 blocks
    dim3 block(256, 1, 1);
    lncc_main<<<grid, block, 0, stream>>>(src, tgt, partial);
    lncc_finalize<<<dim3(1), dim3(256), 0, stream>>>(partial, out);
}